// Round 1
// baseline (978.918 us; speedup 1.0000x reference)
//
#include <hip/hip_runtime.h>
#include <cstdint>
#include <cstddef>

#define NTOK 8192
#define DMODEL 768
#define NEXP 16
#define HDIM 3072
#define CAP 640
#define LDP 72  // padded LDS row (elements); 72*2=144 B, multiple of 16

typedef __attribute__((ext_vector_type(8))) short short8v;
typedef __attribute__((ext_vector_type(4))) float f32x4;

static __device__ __forceinline__ unsigned short f2bf(float f){
  union { float f; unsigned int u; } v; v.f = f;
  unsigned int u = v.u;
  unsigned int r = (u + 0x7FFFu + ((u >> 16) & 1u)) >> 16;
  return (unsigned short)r;
}

// ---------------- init expert_tok = -1 ----------------
__global__ void init_tok_kernel(int* __restrict__ expert_tok){
  int i = blockIdx.x * 256 + threadIdx.x;   // 40*256 = 10240 exact
  expert_tok[i] = -1;
}

// ---------------- router: logits, softmax-gate, argmax ----------------
__global__ __launch_bounds__(256) void router_kernel(
    const float* __restrict__ x, const float* __restrict__ Wr,
    int* __restrict__ eid, float* __restrict__ gate)
{
  int t = blockIdx.x * 4 + (threadIdx.x >> 6);
  int lane = threadIdx.x & 63;
  const float* xr = x + (size_t)t * DMODEL;
  float acc[16];
  #pragma unroll
  for (int e = 0; e < 16; e++) acc[e] = 0.f;
  #pragma unroll
  for (int i = 0; i < 12; i++){
    float xv = xr[lane + i * 64];
    const float* wrow = Wr + (size_t)(lane + i * 64) * 16;
    #pragma unroll
    for (int e = 0; e < 16; e++) acc[e] += xv * wrow[e];
  }
  #pragma unroll
  for (int e = 0; e < 16; e++){
    float v = acc[e];
    #pragma unroll
    for (int off = 32; off >= 1; off >>= 1) v += __shfl_xor(v, off, 64);
    acc[e] = v;
  }
  if (lane == 0){
    float mx = acc[0]; int bi = 0;
    #pragma unroll
    for (int e = 1; e < 16; e++) if (acc[e] > mx){ mx = acc[e]; bi = e; }
    float s = 0.f;
    #pragma unroll
    for (int e = 0; e < 16; e++) s += __expf(acc[e] - mx);
    eid[t] = bi;
    gate[t] = 1.0f / s;   // softmax value at the argmax
  }
}

// ---------------- order-preserving slot scan (1 block) ----------------
__global__ __launch_bounds__(256) void scan_route_kernel(
    const int* __restrict__ eid, const float* __restrict__ gate,
    int* __restrict__ expert_tok, float* __restrict__ cw, int* __restrict__ dropped)
{
  __shared__ int hist[256][16];
  int t = threadIdx.x;
  #pragma unroll
  for (int e = 0; e < 16; e++) hist[t][e] = 0;
  __syncthreads();
  for (int i = 0; i < 32; i++){
    int tok = t * 32 + i;
    hist[t][eid[tok]]++;
  }
  __syncthreads();
  if (t < 16){
    int run = 0;
    for (int i = 0; i < 256; i++){ int c = hist[i][t]; hist[i][t] = run; run += c; }
  }
  __syncthreads();
  for (int i = 0; i < 32; i++){
    int tok = t * 32 + i;
    int e = eid[tok];
    int slot = hist[t][e]++;
    if (slot < CAP){
      expert_tok[e * CAP + slot] = tok;
      cw[e * CAP + slot] = gate[tok];
      dropped[tok] = 0;
    } else {
      dropped[tok] = 1;
    }
  }
}

// ---------------- gather x rows -> bf16 [E][C][D] ----------------
__global__ __launch_bounds__(192) void gather_x_kernel(
    const float* __restrict__ x, const int* __restrict__ expert_tok,
    unsigned short* __restrict__ xa)
{
  int ec = blockIdx.x;
  int token = expert_tok[ec];
  int t4 = threadIdx.x * 4;
  ushort4 o;
  if (token >= 0){
    const float4 v = *(const float4*)(x + (size_t)token * DMODEL + t4);
    o.x = f2bf(v.x); o.y = f2bf(v.y); o.z = f2bf(v.z); o.w = f2bf(v.w);
  } else {
    o.x = 0; o.y = 0; o.z = 0; o.w = 0;
  }
  *(ushort4*)(xa + (size_t)ec * DMODEL + t4) = o;
}

// ---------------- transpose-convert [K][Nn] f32 -> [Nn][K] bf16 ----------------
__global__ __launch_bounds__(256) void transpose_cvt_kernel(
    const float* __restrict__ src, unsigned short* __restrict__ dst, int K, int Nn)
{
  __shared__ unsigned short tile[64][80];
  int e = blockIdx.z;
  size_t soff = (size_t)e * K * Nn;
  int k0 = blockIdx.x * 64, n0 = blockIdx.y * 64;
  int t = threadIdx.x;
  int kl = t >> 4;
  int nl4 = (t & 15) * 4;
  #pragma unroll
  for (int i = 0; i < 4; i++){
    int k = kl + i * 16;
    float4 v = *(const float4*)(src + soff + (size_t)(k0 + k) * Nn + n0 + nl4);
    tile[nl4 + 0][k] = f2bf(v.x);
    tile[nl4 + 1][k] = f2bf(v.y);
    tile[nl4 + 2][k] = f2bf(v.z);
    tile[nl4 + 3][k] = f2bf(v.w);
  }
  __syncthreads();
  int n = t >> 2, q = t & 3;
  size_t doff = (size_t)e * Nn * K + (size_t)(n0 + n) * K + k0 + q * 16;
  const uint4* ts = (const uint4*)&tile[n][q * 16];
  *(uint4*)(dst + doff) = ts[0];
  *(uint4*)(dst + doff + 8) = ts[1];
}

// ---------------- GEMM1: xe @ W1 (gate+up) fused swiglu -> act bf16 ----------------
__global__ __launch_bounds__(256, 2) void gemm1_swiglu_kernel(
    const unsigned short* __restrict__ xa,   // [E][640][768]
    const unsigned short* __restrict__ w1t,  // [E][6144][768]
    const float* __restrict__ b1,            // [E][6144]
    unsigned short* __restrict__ act)        // [E][640][3072]
{
  __shared__ unsigned short As [128 * LDP];
  __shared__ unsigned short Bgs[128 * LDP];
  __shared__ unsigned short Bus[128 * LDP];
  const int e  = blockIdx.z;
  const int m0 = blockIdx.x * 128;
  const int n0 = blockIdx.y * 128;
  const int tid  = threadIdx.x;
  const int lane = tid & 63;
  const int wv   = tid >> 6;
  const int wr   = (wv >> 1) * 64;
  const int wc   = (wv & 1) * 64;
  const int fr   = lane & 15;
  const int kg   = lane >> 4;

  const unsigned short* Ag = xa  + ((size_t)e * 640 + m0) * 768;
  const unsigned short* Bg = w1t + ((size_t)e * 6144 + n0) * 768;
  const unsigned short* Bu = w1t + ((size_t)e * 6144 + 3072 + n0) * 768;

  f32x4 accg[4][4], accu[4][4];
  f32x4 zero4 = {0.f, 0.f, 0.f, 0.f};
  #pragma unroll
  for (int m = 0; m < 4; m++)
    #pragma unroll
    for (int n = 0; n < 4; n++){ accg[m][n] = zero4; accu[m][n] = zero4; }

  const int srow = tid >> 3;          // +32 per q
  const int sseg = (tid & 7) * 8;     // element offset in 64

  for (int kt = 0; kt < 768; kt += 64){
    uint4 ra[4], rg[4], ru[4];
    #pragma unroll
    for (int q = 0; q < 4; q++){
      int row = srow + q * 32;
      ra[q] = *(const uint4*)(Ag + (size_t)row * 768 + kt + sseg);
      rg[q] = *(const uint4*)(Bg + (size_t)row * 768 + kt + sseg);
      ru[q] = *(const uint4*)(Bu + (size_t)row * 768 + kt + sseg);
    }
    __syncthreads();
    #pragma unroll
    for (int q = 0; q < 4; q++){
      int row = srow + q * 32;
      *(uint4*)(As  + row * LDP + sseg) = ra[q];
      *(uint4*)(Bgs + row * LDP + sseg) = rg[q];
      *(uint4*)(Bus + row * LDP + sseg) = ru[q];
    }
    __syncthreads();
    #pragma unroll
    for (int kk = 0; kk < 2; kk++){
      short8v af[4], bg[4], bu[4];
      #pragma unroll
      for (int m = 0; m < 4; m++)
        af[m] = *(const short8v*)(As + (wr + m * 16 + fr) * LDP + kk * 32 + kg * 8);
      #pragma unroll
      for (int n = 0; n < 4; n++){
        bg[n] = *(const short8v*)(Bgs + (wc + n * 16 + fr) * LDP + kk * 32 + kg * 8);
        bu[n] = *(const short8v*)(Bus + (wc + n * 16 + fr) * LDP + kk * 32 + kg * 8);
      }
      #pragma unroll
      for (int m = 0; m < 4; m++)
        #pragma unroll
        for (int n = 0; n < 4; n++){
          accg[m][n] = __builtin_amdgcn_mfma_f32_16x16x32_bf16(af[m], bg[n], accg[m][n], 0, 0, 0);
          accu[m][n] = __builtin_amdgcn_mfma_f32_16x16x32_bf16(af[m], bu[n], accu[m][n], 0, 0, 0);
        }
    }
  }
  // epilogue: h_gate/h_up (+bias) -> silu(g)*u -> bf16 act
  #pragma unroll
  for (int n = 0; n < 4; n++){
    int col = n0 + wc + n * 16 + fr;
    float b_g = b1[(size_t)e * 6144 + col];
    float b_u = b1[(size_t)e * 6144 + 3072 + col];
    #pragma unroll
    for (int m = 0; m < 4; m++){
      #pragma unroll
      for (int r = 0; r < 4; r++){
        int row = m0 + wr + m * 16 + kg * 4 + r;
        float hg = accg[m][n][r] + b_g;
        float hu = accu[m][n][r] + b_u;
        float s = (hg / (1.0f + __expf(-hg))) * hu;
        act[((size_t)e * 640 + row) * 3072 + col] = f2bf(s);
      }
    }
  }
}

// ---------------- GEMM2: act @ W2 + b2, * combine weight, scatter to out ----------------
__global__ __launch_bounds__(256, 2) void gemm2_combine_kernel(
    const unsigned short* __restrict__ act,  // [E][640][3072]
    const unsigned short* __restrict__ w2t,  // [E][768][3072]
    const float* __restrict__ b2,            // [E][768]
    const int* __restrict__ expert_tok,      // [E][640]
    const float* __restrict__ cw,            // [E][640]
    float* __restrict__ out)                 // [N][768]
{
  __shared__ unsigned short As[128 * LDP];
  __shared__ unsigned short Bs[128 * LDP];
  const int e  = blockIdx.z;
  const int m0 = blockIdx.x * 128;
  const int n0 = blockIdx.y * 128;
  const int tid  = threadIdx.x;
  const int lane = tid & 63;
  const int wv   = tid >> 6;
  const int wr   = (wv >> 1) * 64;
  const int wc   = (wv & 1) * 64;
  const int fr   = lane & 15;
  const int kg   = lane >> 4;

  const unsigned short* Ag = act + ((size_t)e * 640 + m0) * 3072;
  const unsigned short* Bg = w2t + ((size_t)e * 768 + n0) * 3072;

  f32x4 acc[4][4];
  f32x4 zero4 = {0.f, 0.f, 0.f, 0.f};
  #pragma unroll
  for (int m = 0; m < 4; m++)
    #pragma unroll
    for (int n = 0; n < 4; n++) acc[m][n] = zero4;

  const int srow = tid >> 3;
  const int sseg = (tid & 7) * 8;

  for (int kt = 0; kt < 3072; kt += 64){
    uint4 ra[4], rb[4];
    #pragma unroll
    for (int q = 0; q < 4; q++){
      int row = srow + q * 32;
      ra[q] = *(const uint4*)(Ag + (size_t)row * 3072 + kt + sseg);
      rb[q] = *(const uint4*)(Bg + (size_t)row * 3072 + kt + sseg);
    }
    __syncthreads();
    #pragma unroll
    for (int q = 0; q < 4; q++){
      int row = srow + q * 32;
      *(uint4*)(As + row * LDP + sseg) = ra[q];
      *(uint4*)(Bs + row * LDP + sseg) = rb[q];
    }
    __syncthreads();
    #pragma unroll
    for (int kk = 0; kk < 2; kk++){
      short8v af[4], bf[4];
      #pragma unroll
      for (int m = 0; m < 4; m++)
        af[m] = *(const short8v*)(As + (wr + m * 16 + fr) * LDP + kk * 32 + kg * 8);
      #pragma unroll
      for (int n = 0; n < 4; n++)
        bf[n] = *(const short8v*)(Bs + (wc + n * 16 + fr) * LDP + kk * 32 + kg * 8);
      #pragma unroll
      for (int m = 0; m < 4; m++)
        #pragma unroll
        for (int n = 0; n < 4; n++)
          acc[m][n] = __builtin_amdgcn_mfma_f32_16x16x32_bf16(af[m], bf[n], acc[m][n], 0, 0, 0);
    }
  }
  float b2v[4];
  #pragma unroll
  for (int n = 0; n < 4; n++) b2v[n] = b2[(size_t)e * 768 + n0 + wc + n * 16 + fr];
  #pragma unroll
  for (int m = 0; m < 4; m++){
    #pragma unroll
    for (int r = 0; r < 4; r++){
      int row = m0 + wr + m * 16 + kg * 4 + r;
      int token = expert_tok[e * CAP + row];
      if (token >= 0){
        float w = cw[e * CAP + row];
        #pragma unroll
        for (int n = 0; n < 4; n++){
          int col = n0 + wc + n * 16 + fr;
          out[(size_t)token * 768 + col] = (acc[m][n][r] + b2v[n]) * w;
        }
      }
    }
  }
}

// ---------------- dense fallback for dropped tokens only ----------------
__global__ __launch_bounds__(256) void fallback_kernel(
    const float* __restrict__ x,
    const float* __restrict__ W1f, const float* __restrict__ b1f,
    const float* __restrict__ W2f, const float* __restrict__ b2f,
    const int* __restrict__ dropped, float* __restrict__ out)
{
  int t = blockIdx.x;
  if (dropped[t] == 0) return;
  __shared__ float xs[768];
  __shared__ float hs[6144];
  int tid = threadIdx.x;
  for (int d = tid; d < 768; d += 256) xs[d] = x[(size_t)t * 768 + d];
  __syncthreads();
  for (int j = tid; j < 6144; j += 256){
    float a = b1f[j];
    for (int d = 0; d < 768; d++) a += xs[d] * W1f[(size_t)d * 6144 + j];
    hs[j] = a;
  }
  __syncthreads();
  for (int j = tid; j < 3072; j += 256){
    float hg = hs[j], hu = hs[j + 3072];
    hs[j] = (hg / (1.0f + __expf(-hg))) * hu;
  }
  __syncthreads();
  for (int d = tid; d < 768; d += 256){
    float a = b2f[d];
    for (int h = 0; h < 3072; h++) a += hs[h] * W2f[(size_t)h * 768 + d];
    out[(size_t)t * 768 + d] = a;   // FALLBACK_W = 1.0
  }
}

extern "C" void kernel_launch(void* const* d_in, const int* in_sizes, int n_in,
                              void* d_out, int out_size, void* d_ws, size_t ws_size,
                              hipStream_t stream) {
  const float* x   = (const float*)d_in[0];
  const float* Wr  = (const float*)d_in[1];
  const float* W1  = (const float*)d_in[2];
  const float* b1  = (const float*)d_in[3];
  const float* W2  = (const float*)d_in[4];
  const float* b2  = (const float*)d_in[5];
  const float* W1f = (const float*)d_in[6];
  const float* b1f = (const float*)d_in[7];
  const float* W2f = (const float*)d_in[8];
  const float* b2f = (const float*)d_in[9];
  float* out = (float*)d_out;

  char* ws = (char*)d_ws;
  int*            expert_tok = (int*)  (ws + 0);          // 16*640*4      = 40960
  float*          cw         = (float*)(ws + 40960);      // 40960
  int*            eid        = (int*)  (ws + 81920);      // 8192*4
  float*          gate       = (float*)(ws + 114688);     // 8192*4
  int*            drop       = (int*)  (ws + 147456);     // 8192*4
  unsigned short* xa         = (unsigned short*)(ws + 180224);     // 16*640*768*2   = 15728640
  unsigned short* act        = (unsigned short*)(ws + 15908864);   // 16*640*3072*2  = 62914560
  unsigned short* w1t        = (unsigned short*)(ws + 78823424);   // 16*6144*768*2  = 150994944
  unsigned short* w2t        = (unsigned short*)(ws + 229818368);  // 16*768*3072*2  = 75497472
  // total ws use: 305315840 bytes

  init_tok_kernel<<<40, 256, 0, stream>>>(expert_tok);
  router_kernel<<<2048, 256, 0, stream>>>(x, Wr, eid, gate);
  scan_route_kernel<<<1, 256, 0, stream>>>(eid, gate, expert_tok, cw, drop);
  gather_x_kernel<<<16 * CAP, 192, 0, stream>>>(x, expert_tok, xa);
  transpose_cvt_kernel<<<dim3(12, 96, 16), 256, 0, stream>>>(W1, w1t, 768, 6144);
  transpose_cvt_kernel<<<dim3(48, 12, 16), 256, 0, stream>>>(W2, w2t, 3072, 768);
  gemm1_swiglu_kernel<<<dim3(5, 24, 16), 256, 0, stream>>>(xa, w1t, b1, act);
  gemm2_combine_kernel<<<dim3(5, 6, 16), 256, 0, stream>>>(act, w2t, b2, expert_tok, cw, out);
  fallback_kernel<<<NTOK, 256, 0, stream>>>(x, W1f, b1f, W2f, b2f, drop, out);
}

// Round 2
// 500.141 us; speedup vs baseline: 1.9573x; 1.9573x over previous
//
#include <hip/hip_runtime.h>
#include <cstdint>
#include <cstddef>

#define NTOK 8192
#define DMODEL 768
#define NEXP 16
#define HDIM 3072
#define CAP 640

typedef __attribute__((ext_vector_type(8))) short short8v;
typedef __attribute__((ext_vector_type(4))) float f32x4;

static __device__ __forceinline__ unsigned short f2bf(float f){
  union { float f; unsigned int u; } v; v.f = f;
  unsigned int u = v.u;
  unsigned int r = (u + 0x7FFFu + ((u >> 16) & 1u)) >> 16;
  return (unsigned short)r;
}

// async global(16B per lane) -> LDS (wave-uniform base + lane*16)
static __device__ __forceinline__ void gload16(const unsigned short* g, unsigned short* l){
  __builtin_amdgcn_global_load_lds(
      (const __attribute__((address_space(1))) unsigned int*)g,
      (__attribute__((address_space(3))) unsigned int*)l, 16, 0, 0);
}

// ---------------- init expert_tok = -1 ----------------
__global__ void init_tok_kernel(int* __restrict__ expert_tok){
  int i = blockIdx.x * 256 + threadIdx.x;   // 40*256 = 10240 exact
  expert_tok[i] = -1;
}

// ---------------- router: logits, softmax-gate, argmax ----------------
__global__ __launch_bounds__(256) void router_kernel(
    const float* __restrict__ x, const float* __restrict__ Wr,
    int* __restrict__ eid, float* __restrict__ gate)
{
  int t = blockIdx.x * 4 + (threadIdx.x >> 6);
  int lane = threadIdx.x & 63;
  const float* xr = x + (size_t)t * DMODEL;
  float acc[16];
  #pragma unroll
  for (int e = 0; e < 16; e++) acc[e] = 0.f;
  #pragma unroll
  for (int i = 0; i < 12; i++){
    float xv = xr[lane + i * 64];
    const float* wrow = Wr + (size_t)(lane + i * 64) * 16;
    #pragma unroll
    for (int e = 0; e < 16; e++) acc[e] += xv * wrow[e];
  }
  #pragma unroll
  for (int e = 0; e < 16; e++){
    float v = acc[e];
    #pragma unroll
    for (int off = 32; off >= 1; off >>= 1) v += __shfl_xor(v, off, 64);
    acc[e] = v;
  }
  if (lane == 0){
    float mx = acc[0]; int bi = 0;
    #pragma unroll
    for (int e = 1; e < 16; e++) if (acc[e] > mx){ mx = acc[e]; bi = e; }
    float s = 0.f;
    #pragma unroll
    for (int e = 0; e < 16; e++) s += __expf(acc[e] - mx);
    eid[t] = bi;
    gate[t] = 1.0f / s;   // softmax value at the argmax
  }
}

// ---------------- order-preserving slot scan (1 block) ----------------
__global__ __launch_bounds__(256) void scan_route_kernel(
    const int* __restrict__ eid, const float* __restrict__ gate,
    int* __restrict__ expert_tok, float* __restrict__ cw, int* __restrict__ dropped)
{
  __shared__ int hist[256][16];
  int t = threadIdx.x;
  #pragma unroll
  for (int e = 0; e < 16; e++) hist[t][e] = 0;
  __syncthreads();
  for (int i = 0; i < 32; i++){
    int tok = t * 32 + i;
    hist[t][eid[tok]]++;
  }
  __syncthreads();
  if (t < 16){
    int run = 0;
    for (int i = 0; i < 256; i++){ int c = hist[i][t]; hist[i][t] = run; run += c; }
  }
  __syncthreads();
  for (int i = 0; i < 32; i++){
    int tok = t * 32 + i;
    int e = eid[tok];
    int slot = hist[t][e]++;
    if (slot < CAP){
      expert_tok[e * CAP + slot] = tok;
      cw[e * CAP + slot] = gate[tok];
      dropped[tok] = 0;
    } else {
      dropped[tok] = 1;
    }
  }
}

// ---------------- gather x rows -> bf16 [E][C][D] ----------------
__global__ __launch_bounds__(192) void gather_x_kernel(
    const float* __restrict__ x, const int* __restrict__ expert_tok,
    unsigned short* __restrict__ xa)
{
  int ec = blockIdx.x;
  int token = expert_tok[ec];
  int t4 = threadIdx.x * 4;
  ushort4 o;
  if (token >= 0){
    const float4 v = *(const float4*)(x + (size_t)token * DMODEL + t4);
    o.x = f2bf(v.x); o.y = f2bf(v.y); o.z = f2bf(v.z); o.w = f2bf(v.w);
  } else {
    o.x = 0; o.y = 0; o.z = 0; o.w = 0;
  }
  *(ushort4*)(xa + (size_t)ec * DMODEL + t4) = o;
}

// ---------------- transpose-convert [K][Nn] f32 -> [Nn][K] bf16 ----------------
__global__ __launch_bounds__(256) void transpose_cvt_kernel(
    const float* __restrict__ src, unsigned short* __restrict__ dst, int K, int Nn)
{
  __shared__ unsigned short tile[64][80];
  int e = blockIdx.z;
  size_t soff = (size_t)e * K * Nn;
  int k0 = blockIdx.x * 64, n0 = blockIdx.y * 64;
  int t = threadIdx.x;
  int kl = t >> 4;
  int nl4 = (t & 15) * 4;
  #pragma unroll
  for (int i = 0; i < 4; i++){
    int k = kl + i * 16;
    float4 v = *(const float4*)(src + soff + (size_t)(k0 + k) * Nn + n0 + nl4);
    tile[nl4 + 0][k] = f2bf(v.x);
    tile[nl4 + 1][k] = f2bf(v.y);
    tile[nl4 + 2][k] = f2bf(v.z);
    tile[nl4 + 3][k] = f2bf(v.w);
  }
  __syncthreads();
  int n = t >> 2, q = t & 3;
  size_t doff = (size_t)e * Nn * K + (size_t)(n0 + n) * K + k0 + q * 16;
  const uint4* ts = (const uint4*)&tile[n][q * 16];
  *(uint4*)(dst + doff) = ts[0];
  *(uint4*)(dst + doff + 8) = ts[1];
}

// ---------------- GEMM1: xe @ W1 (gate+up) fused swiglu -> act bf16 ----------------
// m97-style: linear LDS [rows][64], global_load_lds 16B staging, 2 barriers/iter.
__global__ __launch_bounds__(256, 2) void gemm1_swiglu_kernel(
    const unsigned short* __restrict__ xa,   // [E][640][768]
    const unsigned short* __restrict__ w1t,  // [E][6144][768]
    const float* __restrict__ b1,            // [E][6144]
    unsigned short* __restrict__ act)        // [E][640][3072]
{
  __shared__ unsigned short As [128 * 64];
  __shared__ unsigned short Bgs[128 * 64];
  __shared__ unsigned short Bus[128 * 64];
  const int e  = blockIdx.z;
  const int m0 = blockIdx.x * 128;
  const int n0 = blockIdx.y * 128;
  const int tid  = threadIdx.x;
  const int lane = tid & 63;
  const int wv   = tid >> 6;
  const int wr   = (wv >> 1) * 64;
  const int wc   = (wv & 1) * 64;
  const int fr   = lane & 15;
  const int kg   = lane >> 4;

  const unsigned short* Ag = xa  + ((size_t)e * 640 + m0) * 768;
  const unsigned short* Bg = w1t + ((size_t)e * 6144 + n0) * 768;
  const unsigned short* Bu = w1t + ((size_t)e * 6144 + 3072 + n0) * 768;

  // staging map: call c covers rows c*32..c*32+31; wave wv rows wv*8..wv*8+7
  const int srow = wv * 8 + (lane >> 3);   // row within 32-row chunk
  const int scol = (lane & 7) * 8;         // element offset (8 bf16 = 16B)
  unsigned short* ldsA = As  + wv * 512;   // + c*2048 per call
  unsigned short* ldsG = Bgs + wv * 512;
  unsigned short* ldsU = Bus + wv * 512;

  f32x4 accg[4][4], accu[4][4];
  f32x4 zero4 = {0.f, 0.f, 0.f, 0.f};
  #pragma unroll
  for (int m = 0; m < 4; m++)
    #pragma unroll
    for (int n = 0; n < 4; n++){ accg[m][n] = zero4; accu[m][n] = zero4; }

  for (int kt = 0; kt < 768; kt += 64){
    #pragma unroll
    for (int c = 0; c < 4; c++){
      int r = c * 32 + srow;
      gload16(Ag + (size_t)r * 768 + kt + scol, ldsA + c * 2048);
      gload16(Bg + (size_t)r * 768 + kt + scol, ldsG + c * 2048);
      gload16(Bu + (size_t)r * 768 + kt + scol, ldsU + c * 2048);
    }
    __syncthreads();   // drains vmcnt -> tiles ready
    #pragma unroll
    for (int kk = 0; kk < 2; kk++){
      short8v af[4], bg[4], bu[4];
      #pragma unroll
      for (int m = 0; m < 4; m++)
        af[m] = *(const short8v*)(As + (wr + m * 16 + fr) * 64 + kk * 32 + kg * 8);
      #pragma unroll
      for (int n = 0; n < 4; n++){
        bg[n] = *(const short8v*)(Bgs + (wc + n * 16 + fr) * 64 + kk * 32 + kg * 8);
        bu[n] = *(const short8v*)(Bus + (wc + n * 16 + fr) * 64 + kk * 32 + kg * 8);
      }
      #pragma unroll
      for (int m = 0; m < 4; m++)
        #pragma unroll
        for (int n = 0; n < 4; n++){
          accg[m][n] = __builtin_amdgcn_mfma_f32_16x16x32_bf16(af[m], bg[n], accg[m][n], 0, 0, 0);
          accu[m][n] = __builtin_amdgcn_mfma_f32_16x16x32_bf16(af[m], bu[n], accu[m][n], 0, 0, 0);
        }
    }
    __syncthreads();   // all reads done before next stage overwrites
  }
  // epilogue: h_gate/h_up (+bias) -> silu(g)*u -> bf16 act
  #pragma unroll
  for (int n = 0; n < 4; n++){
    int col = n0 + wc + n * 16 + fr;
    float b_g = b1[(size_t)e * 6144 + col];
    float b_u = b1[(size_t)e * 6144 + 3072 + col];
    #pragma unroll
    for (int m = 0; m < 4; m++){
      #pragma unroll
      for (int r = 0; r < 4; r++){
        int row = m0 + wr + m * 16 + kg * 4 + r;
        float hg = accg[m][n][r] + b_g;
        float hu = accu[m][n][r] + b_u;
        float s = (hg / (1.0f + __expf(-hg))) * hu;
        act[((size_t)e * 640 + row) * 3072 + col] = f2bf(s);
      }
    }
  }
}

// ---------------- GEMM2: act @ W2 + b2 -> dense y [E][640][768] f32 ----------------
// BM=64 x BN=128 -> 960 blocks for latency hiding.
__global__ __launch_bounds__(256, 2) void gemm2_kernel(
    const unsigned short* __restrict__ act,  // [E][640][3072]
    const unsigned short* __restrict__ w2t,  // [E][768][3072]
    const float* __restrict__ b2,            // [E][768]
    float* __restrict__ y)                   // [E][640][768]
{
  __shared__ unsigned short As[64 * 64];
  __shared__ unsigned short Bs[128 * 64];
  const int e  = blockIdx.z;
  const int m0 = blockIdx.x * 64;
  const int n0 = blockIdx.y * 128;
  const int tid  = threadIdx.x;
  const int lane = tid & 63;
  const int wv   = tid >> 6;
  const int wr   = (wv >> 1) * 32;
  const int wc   = (wv & 1) * 64;
  const int fr   = lane & 15;
  const int kg   = lane >> 4;

  const unsigned short* Ag = act + ((size_t)e * 640 + m0) * 3072;
  const unsigned short* Bg = w2t + ((size_t)e * 768 + n0) * 3072;

  const int srow = wv * 8 + (lane >> 3);
  const int scol = (lane & 7) * 8;
  unsigned short* ldsA = As + wv * 512;
  unsigned short* ldsB = Bs + wv * 512;

  f32x4 acc[2][4];
  f32x4 zero4 = {0.f, 0.f, 0.f, 0.f};
  #pragma unroll
  for (int m = 0; m < 2; m++)
    #pragma unroll
    for (int n = 0; n < 4; n++) acc[m][n] = zero4;

  for (int kt = 0; kt < 3072; kt += 64){
    #pragma unroll
    for (int c = 0; c < 2; c++)
      gload16(Ag + (size_t)(c * 32 + srow) * 3072 + kt + scol, ldsA + c * 2048);
    #pragma unroll
    for (int c = 0; c < 4; c++)
      gload16(Bg + (size_t)(c * 32 + srow) * 3072 + kt + scol, ldsB + c * 2048);
    __syncthreads();
    #pragma unroll
    for (int kk = 0; kk < 2; kk++){
      short8v af[2], bf[4];
      #pragma unroll
      for (int m = 0; m < 2; m++)
        af[m] = *(const short8v*)(As + (wr + m * 16 + fr) * 64 + kk * 32 + kg * 8);
      #pragma unroll
      for (int n = 0; n < 4; n++)
        bf[n] = *(const short8v*)(Bs + (wc + n * 16 + fr) * 64 + kk * 32 + kg * 8);
      #pragma unroll
      for (int m = 0; m < 2; m++)
        #pragma unroll
        for (int n = 0; n < 4; n++)
          acc[m][n] = __builtin_amdgcn_mfma_f32_16x16x32_bf16(af[m], bf[n], acc[m][n], 0, 0, 0);
    }
    __syncthreads();
  }
  float b2v[4];
  #pragma unroll
  for (int n = 0; n < 4; n++) b2v[n] = b2[(size_t)e * 768 + n0 + wc + n * 16 + fr];
  #pragma unroll
  for (int m = 0; m < 2; m++){
    #pragma unroll
    for (int r = 0; r < 4; r++){
      int row = m0 + wr + m * 16 + kg * 4 + r;
      #pragma unroll
      for (int n = 0; n < 4; n++){
        int col = n0 + wc + n * 16 + fr;
        y[((size_t)e * 640 + row) * 768 + col] = acc[m][n][r] + b2v[n];
      }
    }
  }
}

// ---------------- combine-weight scatter: y[e][c] * cw -> out[token] ----------------
__global__ __launch_bounds__(192) void combine_scatter_kernel(
    const float* __restrict__ y, const int* __restrict__ expert_tok,
    const float* __restrict__ cw, float* __restrict__ out)
{
  int ec = blockIdx.x;
  int token = expert_tok[ec];
  if (token < 0) return;
  float w = cw[ec];
  int t4 = threadIdx.x * 4;
  float4 v = *(const float4*)(y + (size_t)ec * 768 + t4);
  v.x *= w; v.y *= w; v.z *= w; v.w *= w;
  *(float4*)(out + (size_t)token * 768 + t4) = v;
}

// ---------------- dense fallback for dropped tokens only ----------------
__global__ __launch_bounds__(256) void fallback_kernel(
    const float* __restrict__ x,
    const float* __restrict__ W1f, const float* __restrict__ b1f,
    const float* __restrict__ W2f, const float* __restrict__ b2f,
    const int* __restrict__ dropped, float* __restrict__ out)
{
  int t = blockIdx.x;
  if (dropped[t] == 0) return;
  __shared__ float xs[768];
  __shared__ float hs[6144];
  int tid = threadIdx.x;
  for (int d = tid; d < 768; d += 256) xs[d] = x[(size_t)t * 768 + d];
  __syncthreads();
  for (int j = tid; j < 6144; j += 256){
    float a = b1f[j];
    for (int d = 0; d < 768; d++) a += xs[d] * W1f[(size_t)d * 6144 + j];
    hs[j] = a;
  }
  __syncthreads();
  for (int j = tid; j < 3072; j += 256){
    float hg = hs[j], hu = hs[j + 3072];
    hs[j] = (hg / (1.0f + __expf(-hg))) * hu;
  }
  __syncthreads();
  for (int d = tid; d < 768; d += 256){
    float a = b2f[d];
    for (int h = 0; h < 3072; h++) a += hs[h] * W2f[(size_t)h * 768 + d];
    out[(size_t)t * 768 + d] = a;   // FALLBACK_W = 1.0
  }
}

extern "C" void kernel_launch(void* const* d_in, const int* in_sizes, int n_in,
                              void* d_out, int out_size, void* d_ws, size_t ws_size,
                              hipStream_t stream) {
  const float* x   = (const float*)d_in[0];
  const float* Wr  = (const float*)d_in[1];
  const float* W1  = (const float*)d_in[2];
  const float* b1  = (const float*)d_in[3];
  const float* W2  = (const float*)d_in[4];
  const float* b2  = (const float*)d_in[5];
  const float* W1f = (const float*)d_in[6];
  const float* b1f = (const float*)d_in[7];
  const float* W2f = (const float*)d_in[8];
  const float* b2f = (const float*)d_in[9];
  float* out = (float*)d_out;

  char* ws = (char*)d_ws;
  int*            expert_tok = (int*)  (ws + 0);          // 16*640*4      = 40960
  float*          cw         = (float*)(ws + 40960);      // 40960
  int*            eid        = (int*)  (ws + 81920);      // 8192*4
  float*          gate       = (float*)(ws + 114688);     // 8192*4
  int*            drop       = (int*)  (ws + 147456);     // 8192*4
  unsigned short* xa         = (unsigned short*)(ws + 180224);     // 16*640*768*2   = 15728640
  unsigned short* act        = (unsigned short*)(ws + 15908864);   // 16*640*3072*2  = 62914560
  unsigned short* w1t        = (unsigned short*)(ws + 78823424);   // 16*6144*768*2  = 150994944
  unsigned short* w2t        = (unsigned short*)(ws + 229818368);  // 16*768*3072*2  = 75497472
  float*          y          = (float*)(ws + 78823424);   // alias over w1t (dead after gemm1): 16*640*768*4 = 31457280
  // total ws use: 305315840 bytes

  init_tok_kernel<<<40, 256, 0, stream>>>(expert_tok);
  router_kernel<<<2048, 256, 0, stream>>>(x, Wr, eid, gate);
  scan_route_kernel<<<1, 256, 0, stream>>>(eid, gate, expert_tok, cw, drop);
  gather_x_kernel<<<16 * CAP, 192, 0, stream>>>(x, expert_tok, xa);
  transpose_cvt_kernel<<<dim3(12, 96, 16), 256, 0, stream>>>(W1, w1t, 768, 6144);
  transpose_cvt_kernel<<<dim3(48, 12, 16), 256, 0, stream>>>(W2, w2t, 3072, 768);
  gemm1_swiglu_kernel<<<dim3(5, 24, 16), 256, 0, stream>>>(xa, w1t, b1, act);
  gemm2_kernel<<<dim3(10, 6, 16), 256, 0, stream>>>(act, w2t, b2, y);
  combine_scatter_kernel<<<16 * CAP, 192, 0, stream>>>(y, expert_tok, cw, out);
  fallback_kernel<<<NTOK, 256, 0, stream>>>(x, W1f, b1f, W2f, b2f, drop, out);
}